// Round 7
// baseline (300.145 us; speedup 1.0000x reference)
//
#include <hip/hip_runtime.h>

typedef __attribute__((ext_vector_type(8))) short s16x8;
typedef __attribute__((ext_vector_type(4))) float f32x4;

// ---- helpers ---------------------------------------------------------------

static __device__ __forceinline__ unsigned short f2bf(float f) {
  unsigned int u = __float_as_uint(f);
  u += 0x7fffu + ((u >> 16) & 1u);           // round-to-nearest-even
  return (unsigned short)(u >> 16);
}

// XOR-swizzled LDS address: row-major, rowbytes = 1<<shift, 16B-slot swizzle
static __device__ __forceinline__ unsigned short* swz(unsigned short* base, int row,
                                                      int shift, int byte_in_row) {
  int b = (row << shift) + (byte_in_row ^ ((row & 7) << 4));
  return (unsigned short*)((char*)base + b);
}

static __device__ __forceinline__ s16x8 pack8(float4 a, float4 b) {
  s16x8 p;
  p[0] = (short)f2bf(a.x); p[1] = (short)f2bf(a.y);
  p[2] = (short)f2bf(a.z); p[3] = (short)f2bf(a.w);
  p[4] = (short)f2bf(b.x); p[5] = (short)f2bf(b.y);
  p[6] = (short)f2bf(b.z); p[7] = (short)f2bf(b.w);
  return p;
}

// async global->LDS, 16B per lane; LDS dest is wave-uniform base + lane*16
#define GLDS(gp, lp) __builtin_amdgcn_global_load_lds(                        \
    (const __attribute__((address_space(1))) void*)(gp),                      \
    (__attribute__((address_space(3))) void*)(lp), 16, 0, 0)

// stage one 16KB tile image with 8 waves: wave w copies 2KB (2 GLDS/lane)
#define STAGE8(ldsbase, gtile) do {                                           \
    const char* _g = (const char*)(gtile) + (w << 11) + (lane << 4);          \
    char* _l = (char*)(ldsbase) + (w << 11);                                  \
    GLDS(_g,        _l);                                                      \
    GLDS(_g + 1024, _l + 1024);                                               \
  } while (0)

// ---- pack kernel ------------------------------------------------------------
// Per (bh,t): K 64x128 bf16 row-major (256B rows), V transposed to 128x64
// (128B rows). Both stored PRE-XOR-SWIZZLED so linear global_load_lds into LDS
// reproduces the swizzled image.

__global__ void pack_kv(const float* __restrict__ Kg, const float* __restrict__ Vg,
                        unsigned short* __restrict__ Kw, unsigned short* __restrict__ Vw) {
  __shared__ float Vs[8192];
  const int blk = (int)blockIdx.x;          // bh*32 + t
  const float* Kb = Kg + ((size_t)blk << 13);
  const float* Vb = Vg + ((size_t)blk << 13);
  unsigned short* Ko = Kw + ((size_t)blk << 13);
  unsigned short* Vo = Vw + ((size_t)blk << 13);
  int c = (int)threadIdx.x;
  #pragma unroll
  for (int it = 0; it < 4; ++it, c += 256) {
    int r = c >> 4, c8 = (c & 15) << 3;
    int dst = r * 128 + ((((c8 << 1)) ^ ((r & 7) << 4)) >> 1);
    const float4* s4 = (const float4*)(Kb + r * 128 + c8);
    *(s16x8*)(Ko + dst) = pack8(s4[0], s4[1]);
  }
  c = (int)threadIdx.x;
  #pragma unroll
  for (int it = 0; it < 8; ++it, c += 256)
    *(float4*)(Vs + (c << 2)) = *(const float4*)(Vb + (c << 2));
  __syncthreads();
  c = (int)threadIdx.x;
  #pragma unroll
  for (int it = 0; it < 4; ++it, c += 256) {
    int d = c & 127, j0 = (c >> 7) << 3;
    s16x8 p;
    #pragma unroll
    for (int e = 0; e < 8; ++e) p[e] = (short)f2bf(Vs[(j0 + e) * 128 + d]);
    int dst = d * 64 + ((((j0 << 1)) ^ ((d & 7) << 4)) >> 1);
    *(s16x8*)(Vo + dst) = p;
  }
}

// ---- main kernel ------------------------------------------------------------
// B=2 H=16 S=2048 D=128. 512 thr = 8 waves; 128-row Q supertile per block.
// Waves 0-3 -> rows 0-63 (sub 0), waves 4-7 -> rows 64-127 (sub 1); both
// subtiles share each staged K/V tile (halves staging per unit work, halves
// barrier periods). 16x16x32 MFMA structure (r4-proven). Fixed-shift softmax
// (shift=8) in exp2 domain. Grid 512: bid<256 -> Qt=15-..8 (heavy first),
// bid>=256 -> Qt=0..7; bid and bid+256 land on the same CU (round-robin) so
// per-CU work is ~constant.

__global__ __launch_bounds__(512, 4)
void gpsdpa6(const float* __restrict__ Qg, const unsigned short* __restrict__ Kw,
             const unsigned short* __restrict__ Vw, float* __restrict__ Og,
             float* __restrict__ Ag) {
  __shared__ alignas(16) unsigned short KV[4][8192];  // 64KB tile buffers
  __shared__ alignas(16) unsigned short Ps[8][1024];  // per-wave P tile (16KB)

  const int tid  = (int)threadIdx.x;
  const int w    = tid >> 6;
  const int lane = tid & 63;
  const int l15  = lane & 15;
  const int g    = lane >> 4;
  const int sub  = w >> 2;                   // which 64-row subtile
  const int ws3  = w & 3;                    // wave within subtile

  const int bid = (int)blockIdx.x;
  const int bh  = bid & 31;
  const int qsl = bid >> 5;
  const int Qt  = (bid < 256) ? (15 - qsl) : (qsl - 8);
  const int h   = bh & 15;
  const int q0  = Qt << 7;

  const unsigned short* Kb = Kw + ((size_t)(bh << 5) << 13);
  const unsigned short* Vb = Vw + ((size_t)(bh << 5) << 13);
  float* Ob = Og + ((size_t)bh << 18);
  float* Ab = Ag + ((size_t)bh << 22);

  const float L2E = 1.4426950408889634f;
  const float sig = (float)(h + 1);
  const float cst2 = (-1.0f / (2.0f * sig * sig)) * L2E;
  const float scale2 = 0.08838834764831845f * L2E;     // (1/sqrt(128))*log2e
  const float B1 = -11.541560327111707f;               // -8*log2e

  const int rbase = q0 + (sub << 6);
  const int ibase = rbase + (ws3 << 4) + (g << 2);     // +r = global q row
  const int tdiag = (Qt << 1) + sub;
  const int tmax  = (Qt << 1) + 1;

  // Q A-fragments from f32 global (row = rbase + ws3*16 + l15)
  s16x8 aQ[4];
  {
    const float* qr = Qg + ((size_t)bh << 18) +
                      ((size_t)(rbase + (ws3 << 4) + l15) << 7) + (g << 3);
    #pragma unroll
    for (int kc = 0; kc < 4; ++kc) {
      const float4* s4 = (const float4*)(qr + (kc << 5));
      aQ[kc] = pack8(s4[0], s4[1]);
    }
  }

  const f32x4 fzero = {0.f, 0.f, 0.f, 0.f};
  float ps_acc[4] = {0.f, 0.f, 0.f, 0.f};

  // ---------------- pass 1: per-lane partial row sums (K supersteps x2) -----
  const int nst = Qt + 1;                    // tiles 0..2Qt+1, 2 per superstep
  STAGE8(&KV[0][0], Kb);
  STAGE8(&KV[1][0], Kb + ((size_t)1 << 13));
  for (int s = 0; s < nst; ++s) {
    const int cur = s & 1;
    __syncthreads();
    if (s + 1 < nst) {
      STAGE8(&KV[(cur ^ 1) << 1][0],       Kb + ((size_t)(2 * s + 2) << 13));
      STAGE8(&KV[((cur ^ 1) << 1) + 1][0], Kb + ((size_t)(2 * s + 3) << 13));
    }
    #pragma unroll
    for (int half = 0; half < 2; ++half) {
      const int t = 2 * s + half;
      if (t > tdiag) continue;               // sub-0 waves idle on last tile
      unsigned short* Kt = &KV[(cur << 1) + half][0];

      f32x4 acc[4];
      #pragma unroll
      for (int n = 0; n < 4; ++n) acc[n] = fzero;
      __builtin_amdgcn_s_setprio(1);
      #pragma unroll
      for (int kc = 0; kc < 4; ++kc) {
        #pragma unroll
        for (int n = 0; n < 4; ++n) {
          s16x8 bK = *(const s16x8*)swz(Kt, (n << 4) + l15, 8, (kc << 6) + (g << 4));
          acc[n] = __builtin_amdgcn_mfma_f32_16x16x32_bf16(aQ[kc], bK, acc[n], 0, 0, 0);
        }
      }
      __builtin_amdgcn_s_setprio(0);

      const int jb = (t << 6) + l15;
      if (t <= tdiag - 3) {                  // FAR: prior < 1e-14 -> skip
        #pragma unroll
        for (int r = 0; r < 4; ++r) {
          float sm = 0.f;
          #pragma unroll
          for (int n = 0; n < 4; ++n)
            sm += __builtin_amdgcn_exp2f(fmaf(acc[n][r], scale2, B1));
          ps_acc[r] += sm;
        }
      } else if (t < tdiag) {                // NEAR: prior, no mask
        #pragma unroll
        for (int r = 0; r < 4; ++r) {
          const int i = ibase + r;
          float sm = 0.f;
          #pragma unroll
          for (int n = 0; n < 4; ++n) {
            float fd = (float)(i - (jb + (n << 4)));
            float gl = __builtin_amdgcn_exp2f(fd * fd * cst2);
            sm += __builtin_amdgcn_exp2f(fmaf(acc[n][r], scale2, fmaf(gl, L2E, B1)));
          }
          ps_acc[r] += sm;
        }
      } else {                               // DIAG: prior + causal mask
        #pragma unroll
        for (int r = 0; r < 4; ++r) {
          const int i = ibase + r;
          float sm = 0.f;
          #pragma unroll
          for (int n = 0; n < 4; ++n) {
            int dist = i - (jb + (n << 4));
            float fd = (float)dist;
            float gl = __builtin_amdgcn_exp2f(fd * fd * cst2);
            float x = __builtin_amdgcn_exp2f(fmaf(acc[n][r], scale2, fmaf(gl, L2E, B1)));
            sm += (dist >= 0) ? x : 0.f;
          }
          ps_acc[r] += sm;
        }
      }
    }
  }

  // one in-wave shuffle-reduce per pass; fold -8 and 1/sum into exp2 bias
  float lrs2[4];
  #pragma unroll
  for (int r = 0; r < 4; ++r) {
    float v = ps_acc[r];
    #pragma unroll
    for (int mk = 1; mk < 16; mk <<= 1) v += __shfl_xor(v, mk, 64);
    lrs2[r] = B1 - __log2f(v);
  }

  // ---------------- pass 2: probs -> attn + PV ----------------
  f32x4 oacc[8];
  #pragma unroll
  for (int dn = 0; dn < 8; ++dn) oacc[dn] = fzero;

  unsigned short* Pw = &Ps[w][0];

  __syncthreads();                           // pass-1 reads of KV done
  STAGE8(&KV[0][0], Kb);                     // K tile0
  STAGE8(&KV[2][0], Vb);                     // V tile0

  for (int t = 0; t <= tmax; ++t) {
    const int cur = t & 1;
    __syncthreads();
    if (t < tmax) {
      STAGE8(&KV[cur ^ 1][0],       Kb + ((size_t)(t + 1) << 13));
      STAGE8(&KV[2 + (cur ^ 1)][0], Vb + ((size_t)(t + 1) << 13));
    }
    if (t > tdiag) continue;                 // sub-0 waves idle on last tile

    unsigned short* Kt = &KV[cur][0];
    unsigned short* Vt = &KV[2 + cur][0];

    f32x4 acc[4];
    #pragma unroll
    for (int n = 0; n < 4; ++n) acc[n] = fzero;
    __builtin_amdgcn_s_setprio(1);
    #pragma unroll
    for (int kc = 0; kc < 4; ++kc) {
      #pragma unroll
      for (int n = 0; n < 4; ++n) {
        s16x8 bK = *(const s16x8*)swz(Kt, (n << 4) + l15, 8, (kc << 6) + (g << 4));
        acc[n] = __builtin_amdgcn_mfma_f32_16x16x32_bf16(aQ[kc], bK, acc[n], 0, 0, 0);
      }
    }
    __builtin_amdgcn_s_setprio(0);

    const int jb = (t << 6) + l15;
    if (t <= tdiag - 3) {                    // FAR
      #pragma unroll
      for (int r = 0; r < 4; ++r) {
        const int i = ibase + r;
        #pragma unroll
        for (int n = 0; n < 4; ++n) {
          float p = __builtin_amdgcn_exp2f(fmaf(acc[n][r], scale2, lrs2[r]));
          Ab[(size_t)i * 2048 + jb + (n << 4)] = p;
          *swz(Pw, (g << 2) + r, 7, ((n << 4) + l15) << 1) = f2bf(p);
        }
      }
    } else if (t < tdiag) {                  // NEAR
      #pragma unroll
      for (int r = 0; r < 4; ++r) {
        const int i = ibase + r;
        #pragma unroll
        for (int n = 0; n < 4; ++n) {
          float fd = (float)(i - (jb + (n << 4)));
          float gl = __builtin_amdgcn_exp2f(fd * fd * cst2);
          float p = __builtin_amdgcn_exp2f(fmaf(acc[n][r], scale2, fmaf(gl, L2E, lrs2[r])));
          Ab[(size_t)i * 2048 + jb + (n << 4)] = p;
          *swz(Pw, (g << 2) + r, 7, ((n << 4) + l15) << 1) = f2bf(p);
        }
      }
    } else {                                 // DIAG
      #pragma unroll
      for (int r = 0; r < 4; ++r) {
        const int i = ibase + r;
        #pragma unroll
        for (int n = 0; n < 4; ++n) {
          int dist = i - (jb + (n << 4));
          float fd = (float)dist;
          float gl = __builtin_amdgcn_exp2f(fd * fd * cst2);
          float x = __builtin_amdgcn_exp2f(fmaf(acc[n][r], scale2, fmaf(gl, L2E, lrs2[r])));
          float p = (dist >= 0) ? x : 0.f;
          Ab[(size_t)i * 2048 + jb + (n << 4)] = p;
          *swz(Pw, (g << 2) + r, 7, ((n << 4) + l15) << 1) = f2bf(p);
        }
      }
    }

    // PV: A = P (16q x 64j) from own-wave Ps, B = V^T tile
    __builtin_amdgcn_s_setprio(1);
    #pragma unroll
    for (int kc2 = 0; kc2 < 2; ++kc2) {
      s16x8 pa = *(const s16x8*)swz(Pw, l15, 7, (kc2 << 6) + (g << 4));
      #pragma unroll
      for (int dn = 0; dn < 8; ++dn) {
        s16x8 vb = *(const s16x8*)swz(Vt, (dn << 4) + l15, 7, (kc2 << 6) + (g << 4));
        oacc[dn] = __builtin_amdgcn_mfma_f32_16x16x32_bf16(pa, vb, oacc[dn], 0, 0, 0);
      }
    }
    __builtin_amdgcn_s_setprio(0);
  }

  // context write (C-layout: row = 4g+r, col = dn*16 + l15)
  #pragma unroll
  for (int dn = 0; dn < 8; ++dn) {
    #pragma unroll
    for (int r = 0; r < 4; ++r) {
      Ob[((size_t)(ibase + r) << 7) + (dn << 4) + l15] = oacc[dn][r];
    }
  }

  // zero-fill upper triangle: tile col tmax -> sub-0 rows only; beyond -> all
  const float4 z4 = make_float4(0.f, 0.f, 0.f, 0.f);
  {
    float4* dst = (float4*)(Ab + (size_t)q0 * 2048 + (tmax << 6));
    for (int f = tid; f < 1024; f += 512) {        // 64 rows x 16 float4
      int r = f >> 4, cc = f & 15;
      dst[(size_t)r * 512 + cc] = z4;
    }
  }
  for (int tt = tmax + 1; tt < 32; ++tt) {
    float4* dst = (float4*)(Ab + (size_t)q0 * 2048 + (tt << 6));
    #pragma unroll
    for (int k = 0; k < 4; ++k) {                  // 128 rows x 16 float4
      int f = tid + (k << 9);
      int r = f >> 4, cc = f & 15;
      dst[(size_t)r * 512 + cc] = z4;
    }
  }
}

// ---- fallback kernel (round-1, used when ws too small) ----------------------

__global__ __launch_bounds__(256, 2)
void gpsdpa_fb(const float* __restrict__ Qg, const float* __restrict__ Kg,
               const float* __restrict__ Vg, float* __restrict__ Og,
               float* __restrict__ Ag) {
  __shared__ alignas(16) unsigned short Qs[64 * 128];
  __shared__ alignas(16) unsigned short Ksl[64 * 128];
  __shared__ alignas(16) unsigned short Vtl[128 * 64];
  __shared__ alignas(16) unsigned short Ps[4][16 * 64];
  __shared__ float gtab[2048];

  const int tid  = (int)threadIdx.x;
  const int w    = tid >> 6;
  const int lane = tid & 63;
  const int l15  = lane & 15;
  const int g    = lane >> 4;

  const int bh = (int)blockIdx.x & 31;
  const int qt = 31 - ((int)blockIdx.x >> 5);
  const int h  = bh & 15;
  const int q0 = qt << 6;

  const size_t base = (size_t)bh << 18;
  const float* Qb = Qg + base + (size_t)q0 * 128;
  const float* Kb = Kg + base;
  const float* Vb = Vg + base;
  float* Ob = Og + base;
  float* Ab = Ag + ((size_t)bh << 22);

  {
    float sig = (float)(h + 1);
    float c = -1.0f / (2.0f * sig * sig);
    for (int d = tid; d < 2048; d += 256) {
      float fd = (float)d;
      gtab[d] = __expf(fd * fd * c);
    }
  }

  {
    int c = tid;
    #pragma unroll
    for (int it = 0; it < 4; ++it, c += 256) {
      int r = c >> 4, c8 = (c & 15) << 3;
      const float4* s4 = (const float4*)(Qb + (size_t)r * 128 + c8);
      *(s16x8*)swz(Qs, r, 8, c8 * 2) = pack8(s4[0], s4[1]);
    }
  }
  __syncthreads();

  s16x8 aQ[4];
  #pragma unroll
  for (int kc = 0; kc < 4; ++kc)
    aQ[kc] = *(const s16x8*)swz(Qs, (w << 4) + l15, 8, (kc << 6) + (g << 4));

  const float scale = 0.08838834764831845f;
  const int ibase = q0 + (w << 4) + (g << 2);

  float m_r[4], ls_r[4];
  #pragma unroll
  for (int r = 0; r < 4; ++r) { m_r[r] = -3.0e38f; ls_r[r] = 0.0f; }

  const f32x4 fzero = {0.f, 0.f, 0.f, 0.f};

  for (int t = 0; t <= qt; ++t) {
    __syncthreads();
    {
      int c = tid;
      #pragma unroll
      for (int it = 0; it < 4; ++it, c += 256) {
        int r = c >> 4, c8 = (c & 15) << 3;
        const float4* s4 = (const float4*)(Kb + (size_t)((t << 6) + r) * 128 + c8);
        *(s16x8*)swz(Ksl, r, 8, c8 * 2) = pack8(s4[0], s4[1]);
      }
    }
    __syncthreads();

    f32x4 acc[4];
    #pragma unroll
    for (int n = 0; n < 4; ++n) acc[n] = fzero;
    #pragma unroll
    for (int kc = 0; kc < 4; ++kc) {
      #pragma unroll
      for (int n = 0; n < 4; ++n) {
        s16x8 bK = *(const s16x8*)swz(Ksl, (n << 4) + l15, 8, (kc << 6) + (g << 4));
        acc[n] = __builtin_amdgcn_mfma_f32_16x16x32_bf16(aQ[kc], bK, acc[n], 0, 0, 0);
      }
    }

    const int jb = (t << 6) + l15;
    #pragma unroll
    for (int r = 0; r < 4; ++r) {
      const int i = ibase + r;
      float sv[4];
      float mx = -3.0e38f;
      #pragma unroll
      for (int n = 0; n < 4; ++n) {
        int dist = i - (jb + (n << 4));
        float x = (dist >= 0) ? (acc[n][r] * scale + gtab[dist]) : -1.0e9f;
        sv[n] = x;
        mx = fmaxf(mx, x);
      }
      #pragma unroll
      for (int mk = 1; mk < 16; mk <<= 1) mx = fmaxf(mx, __shfl_xor(mx, mk, 64));
      float mn = fmaxf(m_r[r], mx);
      float sm = 0.f;
      #pragma unroll
      for (int n = 0; n < 4; ++n) sm += __expf(sv[n] - mn);
      #pragma unroll
      for (int mk = 1; mk < 16; mk <<= 1) sm += __shfl_xor(sm, mk, 64);
      ls_r[r] = ls_r[r] * __expf(m_r[r] - mn) + sm;
      m_r[r] = mn;
    }
  }

  float rls[4];
  #pragma unroll
  for (int r = 0; r < 4; ++r) rls[r] = 1.0f / ls_r[r];

  f32x4 oacc[8];
  #pragma unroll
  for (int dn = 0; dn < 8; ++dn) oacc[dn] = fzero;

  unsigned short* Pw = &Ps[w][0];

  for (int t = 0; t <= qt; ++t) {
    __syncthreads();
    {
      int c = tid;
      #pragma unroll
      for (int it = 0; it < 4; ++it, c += 256) {
        int r = c >> 4, c8 = (c & 15) << 3;
        const float4* s4 = (const float4*)(Kb + (size_t)((t << 6) + r) * 128 + c8);
        *(s16x8*)swz(Ksl, r, 8, c8 * 2) = pack8(s4[0], s4[1]);
      }
      c = tid;
      #pragma unroll
      for (int it = 0; it < 4; ++it, c += 256) {
        int d = c & 127, j0 = (c >> 7) << 3;
        const float* vs = Vb + (size_t)((t << 6) + j0) * 128 + d;
        s16x8 p;
        #pragma unroll
        for (int e = 0; e < 8; ++e) p[e] = (short)f2bf(vs[(size_t)e * 128]);
        *(s16x8*)swz(Vtl, d, 7, j0 * 2) = p;
      }
    }
    __syncthreads();

    f32x4 acc[4];
    #pragma unroll
    for (int n = 0; n < 4; ++n) acc[n] = fzero;
    #pragma unroll
    for (int kc = 0; kc < 4; ++kc) {
      #pragma unroll
      for (int n = 0; n < 4; ++n) {
        s16x8 bK = *(const s16x8*)swz(Ksl, (n << 4) + l15, 8, (kc << 6) + (g << 4));
        acc[n] = __builtin_amdgcn_mfma_f32_16x16x32_bf16(aQ[kc], bK, acc[n], 0, 0, 0);
      }
    }

    const int jb = (t << 6) + l15;
    #pragma unroll
    for (int r = 0; r < 4; ++r) {
      const int i = ibase + r;
      float* arow = Ab + (size_t)i * 2048 + (t << 6) + l15;
      #pragma unroll
      for (int n = 0; n < 4; ++n) {
        int dist = i - (jb + (n << 4));
        float x = (dist >= 0) ? (acc[n][r] * scale + gtab[dist]) : -1.0e9f;
        float p = __expf(x - m_r[r]) * rls[r];
        arow[n << 4] = p;
        *swz(Pw, (g << 2) + r, 7, ((n << 4) + l15) << 1) = f2bf(p);
      }
    }

    #pragma unroll
    for (int kc2 = 0; kc2 < 2; ++kc2) {
      s16x8 pa = *(const s16x8*)swz(Pw, l15, 7, (kc2 << 6) + (g << 4));
      #pragma unroll
      for (int dn = 0; dn < 8; ++dn) {
        s16x8 vb = *(const s16x8*)swz(Vtl, (dn << 4) + l15, 7, (kc2 << 6) + (g << 4));
        oacc[dn] = __builtin_amdgcn_mfma_f32_16x16x32_bf16(pa, vb, oacc[dn], 0, 0, 0);
      }
    }
  }

  #pragma unroll
  for (int dn = 0; dn < 8; ++dn) {
    #pragma unroll
    for (int r = 0; r < 4; ++r) {
      Ob[(size_t)(ibase + r) * 128 + (dn << 4) + l15] = oacc[dn][r];
    }
  }

  const int jmax = (qt + 1) << 6;
  if (jmax < 2048) {
    for (int r = 0; r < 64; ++r) {
      float4* dst = (float4*)(Ab + (size_t)(q0 + r) * 2048);
      for (int cv = (jmax >> 2) + tid; cv < 512; cv += 256) {
        dst[cv] = make_float4(0.f, 0.f, 0.f, 0.f);
      }
    }
  }
}

// ---- launch ----------------------------------------------------------------

extern "C" void kernel_launch(void* const* d_in, const int* in_sizes, int n_in,
                              void* d_out, int out_size, void* d_ws, size_t ws_size,
                              hipStream_t stream) {
  (void)in_sizes; (void)n_in; (void)out_size;
  const float* Q = (const float*)d_in[0];
  const float* K = (const float*)d_in[1];
  const float* V = (const float*)d_in[2];
  float* ctx  = (float*)d_out;
  float* attn = ctx + (size_t)2 * 16 * 2048 * 128;

  const size_t NEED = (size_t)2 << 24;  // 33.55 MB: Kw + Vtw bf16 images
  if (ws_size >= NEED) {
    unsigned short* Kw = (unsigned short*)d_ws;
    unsigned short* Vw = Kw + ((size_t)1 << 23);
    pack_kv<<<dim3(1024), dim3(256), 0, stream>>>(K, V, Kw, Vw);
    gpsdpa6<<<dim3(512), dim3(512), 0, stream>>>(Q, Kw, Vw, ctx, attn);
  } else {
    gpsdpa_fb<<<dim3(1024), dim3(256), 0, stream>>>(Q, K, V, ctx, attn);
  }
}

// Round 10
// 206.500 us; speedup vs baseline: 1.4535x; 1.4535x over previous
//
#include <hip/hip_runtime.h>

typedef __attribute__((ext_vector_type(8))) short s16x8;
typedef __attribute__((ext_vector_type(4))) float f32x4;

// ---- helpers ---------------------------------------------------------------

static __device__ __forceinline__ unsigned short f2bf(float f) {
  unsigned int u = __float_as_uint(f);
  u += 0x7fffu + ((u >> 16) & 1u);           // round-to-nearest-even
  return (unsigned short)(u >> 16);
}

// XOR-swizzled LDS address: row-major, rowbytes = 1<<shift, 16B-slot swizzle
static __device__ __forceinline__ unsigned short* swz(unsigned short* base, int row,
                                                      int shift, int byte_in_row) {
  int b = (row << shift) + (byte_in_row ^ ((row & 7) << 4));
  return (unsigned short*)((char*)base + b);
}

static __device__ __forceinline__ s16x8 pack8(float4 a, float4 b) {
  s16x8 p;
  p[0] = (short)f2bf(a.x); p[1] = (short)f2bf(a.y);
  p[2] = (short)f2bf(a.z); p[3] = (short)f2bf(a.w);
  p[4] = (short)f2bf(b.x); p[5] = (short)f2bf(b.y);
  p[6] = (short)f2bf(b.z); p[7] = (short)f2bf(b.w);
  return p;
}

// async global->LDS, 16B per lane; LDS dest is wave-uniform base + lane*16
#define GLDS(gp, lp) __builtin_amdgcn_global_load_lds(                        \
    (const __attribute__((address_space(1))) void*)(gp),                      \
    (__attribute__((address_space(3))) void*)(lp), 16, 0, 0)

// stage one 16KB tile image (already swizzled in ws): wave w (of 4) copies 4KB
#define STAGE(ldsbase, gtile) do {                                            \
    const char* _g = (const char*)(gtile) + (w << 12) + (lane << 4);          \
    char* _l = (char*)(ldsbase) + (w << 12);                                  \
    GLDS(_g,        _l);                                                      \
    GLDS(_g + 1024, _l + 1024);                                               \
    GLDS(_g + 2048, _l + 2048);                                               \
    GLDS(_g + 3072, _l + 3072);                                               \
  } while (0)

// numeric constants (exp2 domain)
#define C_L2E   1.4426950408889634f
#define C_SCL2  (0.08838834764831845f * C_L2E)   // (1/sqrt(128))*log2e
#define C_B1    (-11.541560327111707f)           // -8*log2e

// ---- pack kernel ------------------------------------------------------------
// Per (bh,t): K 64x128 bf16 row-major (256B rows), V transposed to 128x64
// (128B rows). Both stored PRE-XOR-SWIZZLED so linear global_load_lds into LDS
// reproduces the swizzled image.

__global__ void pack_kv(const float* __restrict__ Kg, const float* __restrict__ Vg,
                        unsigned short* __restrict__ Kw, unsigned short* __restrict__ Vw) {
  __shared__ float Vs[8192];
  const int blk = (int)blockIdx.x;          // bh*32 + t
  const float* Kb = Kg + ((size_t)blk << 13);
  const float* Vb = Vg + ((size_t)blk << 13);
  unsigned short* Ko = Kw + ((size_t)blk << 13);
  unsigned short* Vo = Vw + ((size_t)blk << 13);
  int c = (int)threadIdx.x;
  #pragma unroll
  for (int it = 0; it < 4; ++it, c += 256) {
    int r = c >> 4, c8 = (c & 15) << 3;
    int dst = r * 128 + ((((c8 << 1)) ^ ((r & 7) << 4)) >> 1);
    const float4* s4 = (const float4*)(Kb + r * 128 + c8);
    *(s16x8*)(Ko + dst) = pack8(s4[0], s4[1]);
  }
  c = (int)threadIdx.x;
  #pragma unroll
  for (int it = 0; it < 8; ++it, c += 256)
    *(float4*)(Vs + (c << 2)) = *(const float4*)(Vb + (c << 2));
  __syncthreads();
  c = (int)threadIdx.x;
  #pragma unroll
  for (int it = 0; it < 4; ++it, c += 256) {
    int d = c & 127, j0 = (c >> 7) << 3;
    s16x8 p;
    #pragma unroll
    for (int e = 0; e < 8; ++e) p[e] = (short)f2bf(Vs[(j0 + e) * 128 + d]);
    int dst = d * 64 + ((((j0 << 1)) ^ ((d & 7) << 4)) >> 1);
    *(s16x8*)(Vo + dst) = p;
  }
}

// ---- main kernel ------------------------------------------------------------
// r4 structure (proven 211us) + r6 arithmetic (proven exp2/folded-1/sum):
// 256 thr / 4 waves / 64-row Q tile of one (b,h); grid 1024, heavy qt first.
// Pass 1: 2-tile K supersteps (dbuf 2x32KB), per-lane partial sums, one
// shuffle-reduce per pass -> lrs2 = -8*log2e - log2(sum). Pass 2: K+V dbuf,
// probs = exp2(acc*scl2 + [prior*log2e] + lrs2), scalar attn stores, Ps tile
// for PV A-frags. Regimes: FAR (t<=qt-3, prior<8e-15 dropped), NEAR (prior,
// no mask), DIAG (prior+mask).

__global__ __launch_bounds__(256, 2)
void gpsdpa9(const float* __restrict__ Qg, const unsigned short* __restrict__ Kw,
             const unsigned short* __restrict__ Vw, float* __restrict__ Og,
             float* __restrict__ Ag) {
  __shared__ alignas(16) unsigned short KV[32768];    // 64KB union region
  __shared__ alignas(16) unsigned short Ps[4][1024];  // per-wave P tile

  const int tid  = (int)threadIdx.x;
  const int w    = tid >> 6;
  const int lane = tid & 63;
  const int l15  = lane & 15;
  const int g    = lane >> 4;

  const int bh = (int)blockIdx.x & 31;
  const int qt = 31 - ((int)blockIdx.x >> 5);
  const int h  = bh & 15;
  const int q0 = qt << 6;

  const float* Qb = Qg + ((size_t)bh << 18) + ((size_t)q0 << 7);
  const unsigned short* Kb = Kw + ((size_t)(bh << 5) << 13);
  const unsigned short* Vb = Vw + ((size_t)(bh << 5) << 13);
  float* Ob = Og + ((size_t)bh << 18) + ((size_t)q0 << 7);
  float* Ab = Ag + ((size_t)bh << 22);

  const float cst2 = (-1.0f / (2.0f * (float)(h + 1) * (float)(h + 1))) * C_L2E;

  // Q A-fragments from f32 global, packed in-register (once per block)
  s16x8 aQ[4];
  {
    const float* qr = Qb + ((w << 4) + l15) * 128 + (g << 3);
    #pragma unroll
    for (int kc = 0; kc < 4; ++kc) {
      const float4* s4 = (const float4*)(qr + (kc << 5));
      aQ[kc] = pack8(s4[0], s4[1]);
    }
  }

  const int ibase = q0 + (w << 4) + (g << 2);
  const f32x4 fzero = {0.f, 0.f, 0.f, 0.f};

  float ps_acc[4] = {0.f, 0.f, 0.f, 0.f};

  // ---------------- pass 1: per-lane partial row sums (2-tile supersteps) ---
  const int nst = (qt >> 1) + 1;
  STAGE(&KV[0],    Kb);
  STAGE(&KV[8192], Kb + ((size_t)1 << 13));
  for (int s = 0; s < nst; ++s) {
    const int cur = s & 1;
    __syncthreads();
    if (s + 1 < nst) {
      unsigned short* nb = &KV[(cur ^ 1) << 14];
      STAGE(nb,        Kb + ((size_t)(2 * s + 2) << 13));
      STAGE(nb + 8192, Kb + ((size_t)(2 * s + 3) << 13));
    }
    #pragma unroll
    for (int half = 0; half < 2; ++half) {
      const int t = 2 * s + half;
      if (t > qt) break;
      unsigned short* Kt = &KV[(cur << 14) + (half << 13)];

      f32x4 acc[4];
      #pragma unroll
      for (int n = 0; n < 4; ++n) acc[n] = fzero;
      __builtin_amdgcn_s_setprio(1);
      #pragma unroll
      for (int kc = 0; kc < 4; ++kc) {
        #pragma unroll
        for (int n = 0; n < 4; ++n) {
          s16x8 bK = *(const s16x8*)swz(Kt, (n << 4) + l15, 8, (kc << 6) + (g << 4));
          acc[n] = __builtin_amdgcn_mfma_f32_16x16x32_bf16(aQ[kc], bK, acc[n], 0, 0, 0);
        }
      }
      __builtin_amdgcn_s_setprio(0);

      const int jb = (t << 6) + l15;
      if (t <= qt - 3) {                     // FAR: prior < 8e-15 -> skip
        #pragma unroll
        for (int r = 0; r < 4; ++r) {
          float sm = 0.f;
          #pragma unroll
          for (int n = 0; n < 4; ++n)
            sm += __builtin_amdgcn_exp2f(fmaf(acc[n][r], C_SCL2, C_B1));
          ps_acc[r] += sm;
        }
      } else if (t < qt) {                   // NEAR: prior, no mask
        #pragma unroll
        for (int r = 0; r < 4; ++r) {
          const int i = ibase + r;
          float sm = 0.f;
          #pragma unroll
          for (int n = 0; n < 4; ++n) {
            float fd = (float)(i - (jb + (n << 4)));
            float gl = __builtin_amdgcn_exp2f(fd * fd * cst2);
            sm += __builtin_amdgcn_exp2f(fmaf(acc[n][r], C_SCL2, fmaf(gl, C_L2E, C_B1)));
          }
          ps_acc[r] += sm;
        }
      } else {                               // DIAG: prior + causal mask
        #pragma unroll
        for (int r = 0; r < 4; ++r) {
          const int i = ibase + r;
          float sm = 0.f;
          #pragma unroll
          for (int n = 0; n < 4; ++n) {
            int dist = i - (jb + (n << 4));
            float fd = (float)dist;
            float gl = __builtin_amdgcn_exp2f(fd * fd * cst2);
            float x = __builtin_amdgcn_exp2f(fmaf(acc[n][r], C_SCL2, fmaf(gl, C_L2E, C_B1)));
            sm += (dist >= 0) ? x : 0.f;
          }
          ps_acc[r] += sm;
        }
      }
    }
  }

  // one shuffle-reduce per pass; fold -8 and 1/sum into the exp2 bias
  float lrs2[4];
  #pragma unroll
  for (int r = 0; r < 4; ++r) {
    float v = ps_acc[r];
    #pragma unroll
    for (int mk = 1; mk < 16; mk <<= 1) v += __shfl_xor(v, mk, 64);
    lrs2[r] = C_B1 - __log2f(v);
  }

  // ---------------- pass 2: probs -> attn + PV ----------------
  f32x4 oacc[8];
  #pragma unroll
  for (int dn = 0; dn < 8; ++dn) oacc[dn] = fzero;

  unsigned short* Pw = &Ps[w][0];

  __syncthreads();                           // pass-1 reads of KV done
  STAGE(&KV[0],     Kb);                     // K tile0
  STAGE(&KV[16384], Vb);                     // V tile0

  for (int t = 0; t <= qt; ++t) {
    const int cur = t & 1;
    __syncthreads();
    if (t < qt) {
      STAGE(&KV[(cur ^ 1) << 13],           Kb + ((size_t)(t + 1) << 13));
      STAGE(&KV[16384 + ((cur ^ 1) << 13)], Vb + ((size_t)(t + 1) << 13));
    }
    unsigned short* Kt = &KV[cur << 13];
    unsigned short* Vt = &KV[16384 + (cur << 13)];

    f32x4 acc[4];
    #pragma unroll
    for (int n = 0; n < 4; ++n) acc[n] = fzero;
    __builtin_amdgcn_s_setprio(1);
    #pragma unroll
    for (int kc = 0; kc < 4; ++kc) {
      #pragma unroll
      for (int n = 0; n < 4; ++n) {
        s16x8 bK = *(const s16x8*)swz(Kt, (n << 4) + l15, 8, (kc << 6) + (g << 4));
        acc[n] = __builtin_amdgcn_mfma_f32_16x16x32_bf16(aQ[kc], bK, acc[n], 0, 0, 0);
      }
    }
    __builtin_amdgcn_s_setprio(0);

    const int jb = (t << 6) + l15;
    if (t <= qt - 3) {                       // FAR
      #pragma unroll
      for (int r = 0; r < 4; ++r) {
        const int i = ibase + r;
        #pragma unroll
        for (int n = 0; n < 4; ++n) {
          float p = __builtin_amdgcn_exp2f(fmaf(acc[n][r], C_SCL2, lrs2[r]));
          Ab[(size_t)i * 2048 + jb + (n << 4)] = p;
          *swz(Pw, (g << 2) + r, 7, ((n << 4) + l15) << 1) = f2bf(p);
        }
      }
    } else if (t < qt) {                     // NEAR
      #pragma unroll
      for (int r = 0; r < 4; ++r) {
        const int i = ibase + r;
        #pragma unroll
        for (int n = 0; n < 4; ++n) {
          float fd = (float)(i - (jb + (n << 4)));
          float gl = __builtin_amdgcn_exp2f(fd * fd * cst2);
          float p = __builtin_amdgcn_exp2f(fmaf(acc[n][r], C_SCL2, fmaf(gl, C_L2E, lrs2[r])));
          Ab[(size_t)i * 2048 + jb + (n << 4)] = p;
          *swz(Pw, (g << 2) + r, 7, ((n << 4) + l15) << 1) = f2bf(p);
        }
      }
    } else {                                 // DIAG
      #pragma unroll
      for (int r = 0; r < 4; ++r) {
        const int i = ibase + r;
        #pragma unroll
        for (int n = 0; n < 4; ++n) {
          int dist = i - (jb + (n << 4));
          float fd = (float)dist;
          float gl = __builtin_amdgcn_exp2f(fd * fd * cst2);
          float x = __builtin_amdgcn_exp2f(fmaf(acc[n][r], C_SCL2, fmaf(gl, C_L2E, lrs2[r])));
          float p = (dist >= 0) ? x : 0.f;
          Ab[(size_t)i * 2048 + jb + (n << 4)] = p;
          *swz(Pw, (g << 2) + r, 7, ((n << 4) + l15) << 1) = f2bf(p);
        }
      }
    }

    // PV: A = P (16q x 64j) from own-wave Ps, B = V^T tile
    __builtin_amdgcn_s_setprio(1);
    #pragma unroll
    for (int kc2 = 0; kc2 < 2; ++kc2) {
      s16x8 pa = *(const s16x8*)swz(Pw, l15, 7, (kc2 << 6) + (g << 4));
      #pragma unroll
      for (int dn = 0; dn < 8; ++dn) {
        s16x8 vb = *(const s16x8*)swz(Vt, (dn << 4) + l15, 7, (kc2 << 6) + (g << 4));
        oacc[dn] = __builtin_amdgcn_mfma_f32_16x16x32_bf16(pa, vb, oacc[dn], 0, 0, 0);
      }
    }
    __builtin_amdgcn_s_setprio(0);
  }

  // context write (C-layout: row = 4g+r, col = dn*16 + l15)
  #pragma unroll
  for (int dn = 0; dn < 8; ++dn) {
    #pragma unroll
    for (int r = 0; r < 4; ++r) {
      Ob[(size_t)((w << 4) + (g << 2) + r) * 128 + (dn << 4) + l15] = oacc[dn][r];
    }
  }

  // zero-fill attn tiles j-tile > qt (upper triangle)
  const float4 z4 = make_float4(0.f, 0.f, 0.f, 0.f);
  for (int tt = qt + 1; tt < 32; ++tt) {
    float4* dst = (float4*)(Ab + (size_t)q0 * 2048 + (tt << 6));
    int f = tid;
    #pragma unroll
    for (int k = 0; k < 4; ++k, f += 256) {
      int r = f >> 4, cc = f & 15;
      dst[(size_t)r * 512 + cc] = z4;
    }
  }
}

// ---- fallback kernel (round-1, used when ws too small) ----------------------

__global__ __launch_bounds__(256, 2)
void gpsdpa_fb(const float* __restrict__ Qg, const float* __restrict__ Kg,
               const float* __restrict__ Vg, float* __restrict__ Og,
               float* __restrict__ Ag) {
  __shared__ alignas(16) unsigned short Qs[64 * 128];
  __shared__ alignas(16) unsigned short Ksl[64 * 128];
  __shared__ alignas(16) unsigned short Vtl[128 * 64];
  __shared__ alignas(16) unsigned short Ps[4][16 * 64];
  __shared__ float gtab[2048];

  const int tid  = (int)threadIdx.x;
  const int w    = tid >> 6;
  const int lane = tid & 63;
  const int l15  = lane & 15;
  const int g    = lane >> 4;

  const int bh = (int)blockIdx.x & 31;
  const int qt = 31 - ((int)blockIdx.x >> 5);
  const int h  = bh & 15;
  const int q0 = qt << 6;

  const size_t base = (size_t)bh << 18;
  const float* Qb = Qg + base + (size_t)q0 * 128;
  const float* Kb = Kg + base;
  const float* Vb = Vg + base;
  float* Ob = Og + base;
  float* Ab = Ag + ((size_t)bh << 22);

  {
    float sig = (float)(h + 1);
    float c = -1.0f / (2.0f * sig * sig);
    for (int d = tid; d < 2048; d += 256) {
      float fd = (float)d;
      gtab[d] = __expf(fd * fd * c);
    }
  }

  {
    int c = tid;
    #pragma unroll
    for (int it = 0; it < 4; ++it, c += 256) {
      int r = c >> 4, c8 = (c & 15) << 3;
      const float4* s4 = (const float4*)(Qb + (size_t)r * 128 + c8);
      *(s16x8*)swz(Qs, r, 8, c8 * 2) = pack8(s4[0], s4[1]);
    }
  }
  __syncthreads();

  s16x8 aQ[4];
  #pragma unroll
  for (int kc = 0; kc < 4; ++kc)
    aQ[kc] = *(const s16x8*)swz(Qs, (w << 4) + l15, 8, (kc << 6) + (g << 4));

  const float scale = 0.08838834764831845f;
  const int ibase = q0 + (w << 4) + (g << 2);

  float m_r[4], ls_r[4];
  #pragma unroll
  for (int r = 0; r < 4; ++r) { m_r[r] = -3.0e38f; ls_r[r] = 0.0f; }

  const f32x4 fzero = {0.f, 0.f, 0.f, 0.f};

  for (int t = 0; t <= qt; ++t) {
    __syncthreads();
    {
      int c = tid;
      #pragma unroll
      for (int it = 0; it < 4; ++it, c += 256) {
        int r = c >> 4, c8 = (c & 15) << 3;
        const float4* s4 = (const float4*)(Kb + (size_t)((t << 6) + r) * 128 + c8);
        *(s16x8*)swz(Ksl, r, 8, c8 * 2) = pack8(s4[0], s4[1]);
      }
    }
    __syncthreads();

    f32x4 acc[4];
    #pragma unroll
    for (int n = 0; n < 4; ++n) acc[n] = fzero;
    #pragma unroll
    for (int kc = 0; kc < 4; ++kc) {
      #pragma unroll
      for (int n = 0; n < 4; ++n) {
        s16x8 bK = *(const s16x8*)swz(Ksl, (n << 4) + l15, 8, (kc << 6) + (g << 4));
        acc[n] = __builtin_amdgcn_mfma_f32_16x16x32_bf16(aQ[kc], bK, acc[n], 0, 0, 0);
      }
    }

    const int jb = (t << 6) + l15;
    #pragma unroll
    for (int r = 0; r < 4; ++r) {
      const int i = ibase + r;
      float sv[4];
      float mx = -3.0e38f;
      #pragma unroll
      for (int n = 0; n < 4; ++n) {
        int dist = i - (jb + (n << 4));
        float x = (dist >= 0) ? (acc[n][r] * scale + gtab[dist]) : -1.0e9f;
        sv[n] = x;
        mx = fmaxf(mx, x);
      }
      #pragma unroll
      for (int mk = 1; mk < 16; mk <<= 1) mx = fmaxf(mx, __shfl_xor(mx, mk, 64));
      float mn = fmaxf(m_r[r], mx);
      float sm = 0.f;
      #pragma unroll
      for (int n = 0; n < 4; ++n) sm += __expf(sv[n] - mn);
      #pragma unroll
      for (int mk = 1; mk < 16; mk <<= 1) sm += __shfl_xor(sm, mk, 64);
      ls_r[r] = ls_r[r] * __expf(m_r[r] - mn) + sm;
      m_r[r] = mn;
    }
  }

  float rls[4];
  #pragma unroll
  for (int r = 0; r < 4; ++r) rls[r] = 1.0f / ls_r[r];

  f32x4 oacc[8];
  #pragma unroll
  for (int dn = 0; dn < 8; ++dn) oacc[dn] = fzero;

  unsigned short* Pw = &Ps[w][0];

  for (int t = 0; t <= qt; ++t) {
    __syncthreads();
    {
      int c = tid;
      #pragma unroll
      for (int it = 0; it < 4; ++it, c += 256) {
        int r = c >> 4, c8 = (c & 15) << 3;
        const float4* s4 = (const float4*)(Kb + (size_t)((t << 6) + r) * 128 + c8);
        *(s16x8*)swz(Ksl, r, 8, c8 * 2) = pack8(s4[0], s4[1]);
      }
      c = tid;
      #pragma unroll
      for (int it = 0; it < 4; ++it, c += 256) {
        int d = c & 127, j0 = (c >> 7) << 3;
        const float* vs = Vb + (size_t)((t << 6) + j0) * 128 + d;
        s16x8 p;
        #pragma unroll
        for (int e = 0; e < 8; ++e) p[e] = (short)f2bf(vs[(size_t)e * 128]);
        *(s16x8*)swz(Vtl, d, 7, j0 * 2) = p;
      }
    }
    __syncthreads();

    f32x4 acc[4];
    #pragma unroll
    for (int n = 0; n < 4; ++n) acc[n] = fzero;
    #pragma unroll
    for (int kc = 0; kc < 4; ++kc) {
      #pragma unroll
      for (int n = 0; n < 4; ++n) {
        s16x8 bK = *(const s16x8*)swz(Ksl, (n << 4) + l15, 8, (kc << 6) + (g << 4));
        acc[n] = __builtin_amdgcn_mfma_f32_16x16x32_bf16(aQ[kc], bK, acc[n], 0, 0, 0);
      }
    }

    const int jb = (t << 6) + l15;
    #pragma unroll
    for (int r = 0; r < 4; ++r) {
      const int i = ibase + r;
      float* arow = Ab + (size_t)i * 2048 + (t << 6) + l15;
      #pragma unroll
      for (int n = 0; n < 4; ++n) {
        int dist = i - (jb + (n << 4));
        float x = (dist >= 0) ? (acc[n][r] * scale + gtab[dist]) : -1.0e9f;
        float p = __expf(x - m_r[r]) * rls[r];
        arow[n << 4] = p;
        *swz(Pw, (g << 2) + r, 7, ((n << 4) + l15) << 1) = f2bf(p);
      }
    }

    #pragma unroll
    for (int kc2 = 0; kc2 < 2; ++kc2) {
      s16x8 pa = *(const s16x8*)swz(Pw, l15, 7, (kc2 << 6) + (g << 4));
      #pragma unroll
      for (int dn = 0; dn < 8; ++dn) {
        s16x8 vb = *(const s16x8*)swz(Vtl, (dn << 4) + l15, 7, (kc2 << 6) + (g << 4));
        oacc[dn] = __builtin_amdgcn_mfma_f32_16x16x32_bf16(pa, vb, oacc[dn], 0, 0, 0);
      }
    }
  }

  #pragma unroll
  for (int dn = 0; dn < 8; ++dn) {
    #pragma unroll
    for (int r = 0; r < 4; ++r) {
      Ob[(size_t)(ibase + r) * 128 + (dn << 4) + l15] = oacc[dn][r];
    }
  }

  const int jmax = (qt + 1) << 6;
  if (jmax < 2048) {
    for (int r = 0; r < 64; ++r) {
      float4* dst = (float4*)(Ab + (size_t)(q0 + r) * 2048);
      for (int cv = (jmax >> 2) + tid; cv < 512; cv += 256) {
        dst[cv] = make_float4(0.f, 0.f, 0.f, 0.f);
      }
    }
  }
}

// ---- launch ----------------------------------------------------------------

extern "C" void kernel_launch(void* const* d_in, const int* in_sizes, int n_in,
                              void* d_out, int out_size, void* d_ws, size_t ws_size,
                              hipStream_t stream) {
  (void)in_sizes; (void)n_in; (void)out_size;
  const float* Q = (const float*)d_in[0];
  const float* K = (const float*)d_in[1];
  const float* V = (const float*)d_in[2];
  float* ctx  = (float*)d_out;
  float* attn = ctx + (size_t)2 * 16 * 2048 * 128;

  const size_t NEED = (size_t)2 << 24;  // 33.55 MB: Kw + Vtw bf16 images
  if (ws_size >= NEED) {
    unsigned short* Kw = (unsigned short*)d_ws;
    unsigned short* Vw = Kw + ((size_t)1 << 23);
    pack_kv<<<dim3(1024), dim3(256), 0, stream>>>(K, V, Kw, Vw);
    gpsdpa9<<<dim3(1024), dim3(256), 0, stream>>>(Q, Kw, Vw, ctx, attn);
  } else {
    gpsdpa_fb<<<dim3(1024), dim3(256), 0, stream>>>(Q, K, V, ctx, attn);
  }
}